// Round 10
// baseline (85.571 us; speedup 1.0000x reference)
//
#include <hip/hip_runtime.h>
#include <stdint.h>

#define NB 2048
#define NCLASSES 80
#define CONF_T 0.05f
#define IOU_T 0.5f
#define MAX_DET 100
#define MAX_PER_CLASS 100

typedef unsigned long long u64;
typedef unsigned int u32;

__device__ __forceinline__ u64 shfl_xor_u64(u64 v, int mask) {
    int lo = (int)(u32)v, hi = (int)(u32)(v >> 32);
    lo = __shfl_xor(lo, mask, 64);
    hi = __shfl_xor(hi, mask, 64);
    return ((u64)(u32)hi << 32) | (u32)lo;
}

// ====================================================================
// Single fused kernel: 1 block (1024 thr, 16 waves) per batch.
// Phase 1: hybrid bitonic sort (r5-validated).
// Phase 2: class counts + wave-parallel prefix (r6) + clsList scatter.
// Phase 3: per-wave sort-free pair-matrix NMS (r9 engine) on 5 classes
//          per wave, per-wave LDS scratch, NO block barriers
//          (same-wave DS ordering + volatile + wave_barrier, r2-pattern).
// Phase 4: compaction + output (r5/r9-validated).
// ====================================================================
__global__ __launch_bounds__(1024) void nms_fused(const float* __restrict__ pred,
                                                  float* __restrict__ out, int B) {
    const int b = blockIdx.x, tid = threadIdx.x;
    const int lane = tid & 63, wave = tid >> 6;        // 16 waves

    __shared__ u64 keys[NB];                           // 16 KB
    __shared__ short kcls[NB];                         // 4 KB
    __shared__ unsigned short clsList[NB];             // 4 KB
    __shared__ int clsCnt[NCLASSES], clsOff[NCLASSES], clsFill[NCLASSES];
    __shared__ u64 wkeyS[16][64];                      // 8 KB per-wave scratch
    __shared__ float wbS[16][4][64];                   // 16 KB (x1,y1,x2,y2)
    __shared__ u64 wmS[16][64];                        // 8 KB
    __shared__ u32 sm[64];                             // suppression bitmap (orig idx)
    __shared__ u64 keptM[32];
    __shared__ int kcnt[32], kbase[32];
    __shared__ unsigned char fstate[NB];               // 2 KB, cnt>64 fallback only

    const float* P = pred + (size_t)b * NB * 6;

    if (tid < NCLASSES) { clsCnt[tid] = 0; clsFill[tid] = 0; }
    if (tid < 64) sm[tid] = 0u;

    // ---- Phase 1: hybrid bitonic sort (validated r4/r5 structure) ----
    const int base = wave * 128;
    const int iA = base + lane, iB = base + 64 + lane;

    float sA = P[iA * 6 + 5];
    float sB = P[iB * 6 + 5];
    u64 A  = (sA > CONF_T) ? (((u64)__float_as_uint(sA) << 32) | (u32)iA) : (u64)(u32)iA;
    u64 Bk = (sB > CONF_T) ? (((u64)__float_as_uint(sB) << 32) | (u32)iB) : (u64)(u32)iB;

    auto phase_local = [&](int k) {
        bool up = ((iA & k) == 0);
        u64 mx = A > Bk ? A : Bk, mn = A > Bk ? Bk : A;
        A = up ? mx : mn;
        Bk = up ? mn : mx;
    };
    auto phase_shfl = [&](int j, int k) {
        u64 pA = shfl_xor_u64(A, j);
        u64 pB = shfl_xor_u64(Bk, j);
        bool low = ((lane & j) == 0);
        bool upA = ((iA & k) == 0);
        bool upB = ((iB & k) == 0);
        A  = (low == upA) ? (A  > pA ? A  : pA) : (A  > pA ? pA : A);
        Bk = (low == upB) ? (Bk > pB ? Bk : pB) : (Bk > pB ? pB : Bk);
    };

    for (int k = 2; k <= 128; k <<= 1) {
        if (k == 128) phase_local(k);
        for (int j = (k == 128 ? 32 : (k >> 1)); j >= 1; j >>= 1) phase_shfl(j, k);
    }
    keys[iA] = A; keys[iB] = Bk;
    __syncthreads();

    for (int k = 256; k <= NB; k <<= 1) {
        for (int j = k >> 1; j >= 128; j >>= 1) {
            const int i1 = ((tid & ~(j - 1)) << 1) | (tid & (j - 1));
            const int i2 = i1 + j;
            const bool up = ((i1 & k) == 0);
            u64 a = keys[i1], c = keys[i2];
            if (up ? (a < c) : (a > c)) { keys[i1] = c; keys[i2] = a; }
            __syncthreads();
        }
        A = keys[iA]; Bk = keys[iB];
        phase_local(k);
        for (int j = 32; j >= 1; j >>= 1) phase_shfl(j, k);
        keys[iA] = A; keys[iB] = Bk;
        __syncthreads();
    }

    // ---- Phase 2: classes + counts -> prefix -> scatter ----
    for (int i = tid; i < NB; i += 1024) {
        u64 k = keys[i];
        int c = -1;
        if (k >> 32) { c = (int)P[(int)(u32)k * 6 + 4]; atomicAdd(&clsCnt[c], 1); }
        kcls[i] = (short)c;
    }
    __syncthreads();
    if (wave == 0) {                                   // wave-parallel prefix (r6)
        int v0 = clsCnt[lane];
        int v1 = (lane < NCLASSES - 64) ? clsCnt[64 + lane] : 0;
        int s0 = v0;
        #pragma unroll
        for (int d = 1; d < 64; d <<= 1) { int t = __shfl_up(s0, d, 64); if (lane >= d) s0 += t; }
        int tot0 = __shfl(s0, 63, 64);
        int s1 = v1;
        #pragma unroll
        for (int d = 1; d < 16; d <<= 1) { int t = __shfl_up(s1, d, 64); if (lane >= d) s1 += t; }
        clsOff[lane] = s0 - v0;
        if (lane < NCLASSES - 64) clsOff[64 + lane] = tot0 + (s1 - v1);
    }
    __syncthreads();
    for (int i = tid; i < NB; i += 1024) {
        int c = kcls[i];
        if (c >= 0) {
            int p = clsOff[c] + atomicAdd(&clsFill[c], 1);
            clsList[p] = (unsigned short)i;
        }
    }
    __syncthreads();

    // ---- Phase 3: per-wave sort-free pair-matrix NMS (r9 engine) ----
    for (int it = 0; it < NCLASSES / 16; ++it) {
        const int c = wave + it * 16;
        const int cnt = clsCnt[c], off = clsOff[c];
        if (cnt < 2) continue;                          // wave-uniform

        if (cnt <= 64) {
            volatile u64* wk = wkeyS[wave];
            volatile float* wx1 = wbS[wave][0];
            volatile float* wy1 = wbS[wave][1];
            volatile float* wx2 = wbS[wave][2];
            volatile float* wy2 = wbS[wave][3];

            u64 mykey = 0ull;
            int orig = 0;
            float x1 = 0.f, y1 = 0.f, x2 = 0.f, y2 = 0.f, ar = 0.f;
            if (lane < cnt) {
                int si = clsList[off + lane];
                mykey = keys[si];
                orig = (int)(u32)mykey;
                const float* q = P + orig * 6;
                float2 p01 = *reinterpret_cast<const float2*>(q);
                float2 p23 = *reinterpret_cast<const float2*>(q + 2);
                x1 = p01.x; y1 = p01.y; x2 = p23.x; y2 = p23.y;
                ar = fmaxf(x2 - x1, 0.f) * fmaxf(y2 - y1, 0.f);
            }
            wk[lane] = mykey;                           // 0 for idle lanes
            wx1[lane] = x1; wy1[lane] = y1; wx2[lane] = x2; wy2[lane] = y2;
            __builtin_amdgcn_wave_barrier();

            u64 mj = 0ull;
            if (lane < cnt) {
                #pragma unroll 8
                for (int i = 0; i < 64; ++i) {
                    u64 ki = wk[i];
                    if (ki > mykey) {                   // i precedes me in global order
                        float bx1 = wx1[i], by1 = wy1[i], bx2 = wx2[i], by2 = wy2[i];
                        float ari = fmaxf(bx2 - bx1, 0.f) * fmaxf(by2 - by1, 0.f);
                        float ix1 = fmaxf(bx1, x1), iy1 = fmaxf(by1, y1);
                        float ix2 = fminf(bx2, x2), iy2 = fminf(by2, y2);
                        float inter = fmaxf(ix2 - ix1, 0.f) * fmaxf(iy2 - iy1, 0.f);
                        float uni = ari + ar - inter;
                        if (inter / fmaxf(uni, 1e-8f) > IOU_T) mj |= 1ull << i;
                    }
                }
            }
            u64 conf = __ballot(mj != 0ull);
            if (conf != 0ull) {                         // rare; wave-uniform
                u64 srcs = mj;
                #pragma unroll
                for (int d = 1; d < 64; d <<= 1) srcs |= shfl_xor_u64(srcs, d);
                volatile u64* wm = wmS[wave];
                wm[lane] = mj;
                __builtin_amdgcn_wave_barrier();

                u64 Cset = srcs | conf;
                u64 keptS = 0ull, rem = Cset;
                while (rem) {                           // tiny redundant scalar greedy
                    u64 t = rem, bestk = 0ull; int bi = -1;
                    while (t) {
                        int i = __ffsll(t) - 1; t &= t - 1;
                        u64 k = wk[i];
                        if (k > bestk) { bestk = k; bi = i; }
                    }
                    rem &= ~(1ull << bi);
                    if ((wm[bi] & keptS) == 0ull) keptS |= 1ull << bi;
                }
                if (lane < cnt && (mj & keptS) != 0ull)
                    atomicOr(&sm[orig >> 5], 1u << (orig & 31));
            }
        } else {
            // ---- exact wave-local fallback (r8 pattern; ~never taken) ----
            volatile unsigned char* vf = fstate + off;  // per-class disjoint range
            for (int e = lane; e < cnt; e += 64) vf[e] = 0;
            __builtin_amdgcn_wave_barrier();
            int keptCount = 0;
            for (;;) {
                u64 best = 0ull; int bi = -1;
                for (int e = lane; e < cnt; e += 64)
                    if (vf[e] == 0) {
                        u64 kv = keys[clsList[off + e]];
                        if (kv > best) { best = kv; bi = e; }
                    }
                for (int d = 32; d >= 1; d >>= 1) {
                    u64 ob = shfl_xor_u64(best, d);
                    int obi = __shfl_xor(bi, d, 64);
                    if (ob > best) { best = ob; bi = obi; }
                }
                if (best == 0ull) break;
                keptCount++;
                int orig = (int)(u32)best;
                const float* q = P + orig * 6;
                float ax1 = q[0], ay1 = q[1], ax2 = q[2], ay2 = q[3];
                float aar = fmaxf(ax2 - ax1, 0.f) * fmaxf(ay2 - ay1, 0.f);
                if (lane == 0) vf[bi] = 1;
                __builtin_amdgcn_wave_barrier();
                for (int e = lane; e < cnt; e += 64) {
                    if (vf[e] == 0) {
                        u64 kv = keys[clsList[off + e]];
                        int o2 = (int)(u32)kv;
                        const float* q2 = P + o2 * 6;
                        float bx1 = q2[0], by1 = q2[1], bx2 = q2[2], by2 = q2[3];
                        float br = fmaxf(bx2 - bx1, 0.f) * fmaxf(by2 - by1, 0.f);
                        float ix1 = fmaxf(ax1, bx1), iy1 = fmaxf(ay1, by1);
                        float ix2 = fminf(ax2, bx2), iy2 = fminf(ay2, by2);
                        float inter = fmaxf(ix2 - ix1, 0.f) * fmaxf(iy2 - iy1, 0.f);
                        if (inter / fmaxf(aar + br - inter, 1e-8f) > IOU_T) {
                            vf[e] = 2;
                            atomicOr(&sm[o2 >> 5], 1u << (o2 & 31));
                        }
                    }
                }
                if (keptCount > MAX_PER_CLASS && lane == 0)
                    atomicOr(&sm[orig >> 5], 1u << (orig & 31));
                __builtin_amdgcn_wave_barrier();
            }
        }
    }
    __syncthreads();

    // ---- Phase 4: compaction + output (validated r5/r9 logic) ----
    for (int cc = wave; cc < 32; cc += 16) {
        u64 k = keys[cc * 64 + lane];
        int orig = (int)(u32)k;
        bool kp = ((k >> 32) != 0) && !((sm[orig >> 5] >> (orig & 31)) & 1u);
        u64 m = __ballot(kp);
        if (lane == 0) { keptM[cc] = m; kcnt[cc] = __popcll(m); }
    }
    __syncthreads();
    if (tid < 32) {
        int s = 0;
        for (int c2 = 0; c2 < tid; ++c2) s += kcnt[c2];
        kbase[tid] = s;
    }
    __syncthreads();

    float* boxes_out   = out + (size_t)b * MAX_DET * 4;
    float* scores_out  = out + (size_t)B * MAX_DET * 4 + (size_t)b * MAX_DET;
    float* classes_out = out + (size_t)B * MAX_DET * 5 + (size_t)b * MAX_DET;
    float* numdet_out  = out + (size_t)B * MAX_DET * 6 + b;

    for (int cc = wave; cc < 32; cc += 16) {
        u64 m = keptM[cc];
        bool kp = (m >> lane) & 1ull;
        int pos = kbase[cc] + __popcll(m & ((1ull << lane) - 1ull));
        if (kp && pos < MAX_DET) {
            u64 k = keys[cc * 64 + lane];
            int orig = (int)(u32)k;
            const float* q = P + orig * 6;
            boxes_out[pos * 4 + 0] = q[0];
            boxes_out[pos * 4 + 1] = q[1];
            boxes_out[pos * 4 + 2] = q[2];
            boxes_out[pos * 4 + 3] = q[3];
            scores_out[pos]  = __uint_as_float((u32)(k >> 32));
            classes_out[pos] = q[4];
        }
    }
    int total = kbase[31] + kcnt[31];
    int nd = total < MAX_DET ? total : MAX_DET;
    for (int p = nd + tid; p < MAX_DET; p += 1024) {
        boxes_out[p * 4 + 0] = 0.f;
        boxes_out[p * 4 + 1] = 0.f;
        boxes_out[p * 4 + 2] = 0.f;
        boxes_out[p * 4 + 3] = 0.f;
        scores_out[p]  = 0.f;
        classes_out[p] = 0.f;
    }
    if (tid == 0) *numdet_out = (float)nd;
}

extern "C" void kernel_launch(void* const* d_in, const int* in_sizes, int n_in,
                              void* d_out, int out_size, void* d_ws, size_t ws_size,
                              hipStream_t stream) {
    const float* pred = (const float*)d_in[0];
    float* out = (float*)d_out;
    const int B = in_sizes[0] / (NB * 6);
    nms_fused<<<B, 1024, 0, stream>>>(pred, out, B);
}

// Round 11
// 61.791 us; speedup vs baseline: 1.3848x; 1.3848x over previous
//
#include <hip/hip_runtime.h>
#include <stdint.h>

#define NB 2048
#define NCLASSES 80
#define CONF_T 0.05f
#define IOU_T 0.5f
#define MAX_DET 100
#define MAX_PER_CLASS 100

typedef unsigned long long u64;
typedef unsigned int u32;

__device__ __forceinline__ u64 shfl_xor_u64(u64 v, int mask) {
    int lo = (int)(u32)v, hi = (int)(u32)(v >> 32);
    lo = __shfl_xor(lo, mask, 64);
    hi = __shfl_xor(hi, mask, 64);
    return ((u64)(u32)hi << 32) | (u32)lo;
}

// ====================================================================
// Single fused kernel (r10 structure, engine DS-traffic fixed):
// Phase 1: hybrid bitonic sort (r5/r10-validated).
// Phase 2: class counts + wave prefix + clsList scatter (r10-validated).
// Phase 3: per-wave pair-matrix NMS — NON-volatile scratch, float4
//          (ds_read_b128) boxes, i<cnt loop: ~4k DS instrs total
//          (was ~30k with volatile scalar reads = the r10 regression).
// Phase 4: compaction + output (r10-validated).
// ====================================================================
__global__ __launch_bounds__(1024) void nms_fused(const float* __restrict__ pred,
                                                  float* __restrict__ out, int B) {
    const int b = blockIdx.x, tid = threadIdx.x;
    const int lane = tid & 63, wave = tid >> 6;        // 16 waves

    __shared__ u64 keys[NB];                           // 16 KB
    __shared__ short kcls[NB];                         // 4 KB
    __shared__ unsigned short clsList[NB];             // 4 KB
    __shared__ int clsCnt[NCLASSES], clsOff[NCLASSES], clsFill[NCLASSES];
    __shared__ u64 wkeyS[16][64];                      // 8 KB per-wave scratch
    __shared__ float4 wb4S[16][64];                    // 16 KB packed boxes
    __shared__ u64 wmS[16][64];                        // 8 KB
    __shared__ u32 sm[64];                             // suppression bitmap
    __shared__ u64 keptM[32];
    __shared__ int kcnt[32], kbase[32];
    __shared__ unsigned char fstate[NB];               // 2 KB fallback only

    const float* P = pred + (size_t)b * NB * 6;

    if (tid < NCLASSES) { clsCnt[tid] = 0; clsFill[tid] = 0; }
    if (tid < 64) sm[tid] = 0u;

    // ---- Phase 1: hybrid bitonic sort (validated) ----
    const int base = wave * 128;
    const int iA = base + lane, iB = base + 64 + lane;

    float sA = P[iA * 6 + 5];
    float sB = P[iB * 6 + 5];
    u64 A  = (sA > CONF_T) ? (((u64)__float_as_uint(sA) << 32) | (u32)iA) : (u64)(u32)iA;
    u64 Bk = (sB > CONF_T) ? (((u64)__float_as_uint(sB) << 32) | (u32)iB) : (u64)(u32)iB;

    auto phase_local = [&](int k) {
        bool up = ((iA & k) == 0);
        u64 mx = A > Bk ? A : Bk, mn = A > Bk ? Bk : A;
        A = up ? mx : mn;
        Bk = up ? mn : mx;
    };
    auto phase_shfl = [&](int j, int k) {
        u64 pA = shfl_xor_u64(A, j);
        u64 pB = shfl_xor_u64(Bk, j);
        bool low = ((lane & j) == 0);
        bool upA = ((iA & k) == 0);
        bool upB = ((iB & k) == 0);
        A  = (low == upA) ? (A  > pA ? A  : pA) : (A  > pA ? pA : A);
        Bk = (low == upB) ? (Bk > pB ? Bk : pB) : (Bk > pB ? pB : Bk);
    };

    for (int k = 2; k <= 128; k <<= 1) {
        if (k == 128) phase_local(k);
        for (int j = (k == 128 ? 32 : (k >> 1)); j >= 1; j >>= 1) phase_shfl(j, k);
    }
    keys[iA] = A; keys[iB] = Bk;
    __syncthreads();

    for (int k = 256; k <= NB; k <<= 1) {
        for (int j = k >> 1; j >= 128; j >>= 1) {
            const int i1 = ((tid & ~(j - 1)) << 1) | (tid & (j - 1));
            const int i2 = i1 + j;
            const bool up = ((i1 & k) == 0);
            u64 a = keys[i1], c = keys[i2];
            if (up ? (a < c) : (a > c)) { keys[i1] = c; keys[i2] = a; }
            __syncthreads();
        }
        A = keys[iA]; Bk = keys[iB];
        phase_local(k);
        for (int j = 32; j >= 1; j >>= 1) phase_shfl(j, k);
        keys[iA] = A; keys[iB] = Bk;
        __syncthreads();
    }

    // ---- Phase 2: classes + counts -> prefix -> scatter (validated) ----
    for (int i = tid; i < NB; i += 1024) {
        u64 k = keys[i];
        int c = -1;
        if (k >> 32) { c = (int)P[(int)(u32)k * 6 + 4]; atomicAdd(&clsCnt[c], 1); }
        kcls[i] = (short)c;
    }
    __syncthreads();
    if (wave == 0) {
        int v0 = clsCnt[lane];
        int v1 = (lane < NCLASSES - 64) ? clsCnt[64 + lane] : 0;
        int s0 = v0;
        #pragma unroll
        for (int d = 1; d < 64; d <<= 1) { int t = __shfl_up(s0, d, 64); if (lane >= d) s0 += t; }
        int tot0 = __shfl(s0, 63, 64);
        int s1 = v1;
        #pragma unroll
        for (int d = 1; d < 16; d <<= 1) { int t = __shfl_up(s1, d, 64); if (lane >= d) s1 += t; }
        clsOff[lane] = s0 - v0;
        if (lane < NCLASSES - 64) clsOff[64 + lane] = tot0 + (s1 - v1);
    }
    __syncthreads();
    for (int i = tid; i < NB; i += 1024) {
        int c = kcls[i];
        if (c >= 0) {
            int p = clsOff[c] + atomicAdd(&clsFill[c], 1);
            clsList[p] = (unsigned short)i;
        }
    }
    __syncthreads();

    // ---- Phase 3: per-wave pair-matrix NMS (DS-lean engine) ----
    for (int it = 0; it < NCLASSES / 16; ++it) {
        const int c = wave + it * 16;
        const int cnt = clsCnt[c], off = clsOff[c];
        if (cnt < 2) continue;                          // wave-uniform

        if (cnt <= 64) {
            u64 mykey = 0ull;
            int orig = 0;
            float x1 = 0.f, y1 = 0.f, x2 = 0.f, y2 = 0.f, ar = 0.f;
            if (lane < cnt) {
                int si = clsList[off + lane];
                mykey = keys[si];
                orig = (int)(u32)mykey;
                const float* q = P + orig * 6;
                float2 p01 = *reinterpret_cast<const float2*>(q);
                float2 p23 = *reinterpret_cast<const float2*>(q + 2);
                x1 = p01.x; y1 = p01.y; x2 = p23.x; y2 = p23.y;
                ar = fmaxf(x2 - x1, 0.f) * fmaxf(y2 - y1, 0.f);
                wkeyS[wave][lane] = mykey;
                wb4S[wave][lane] = make_float4(x1, y1, x2, y2);
            }
            __builtin_amdgcn_wave_barrier();            // compiler fence; same-wave
                                                        // DS ops are HW-ordered
            u64 mj = 0ull;
            if (lane < cnt) {
                for (int i = 0; i < cnt; ++i) {
                    u64 ki = wkeyS[wave][i];            // ds_read_b64 broadcast
                    if (ki > mykey) {                   // i precedes me globally
                        float4 bi = wb4S[wave][i];      // ds_read_b128 broadcast
                        float ari = fmaxf(bi.z - bi.x, 0.f) * fmaxf(bi.w - bi.y, 0.f);
                        float ix1 = fmaxf(bi.x, x1), iy1 = fmaxf(bi.y, y1);
                        float ix2 = fminf(bi.z, x2), iy2 = fminf(bi.w, y2);
                        float inter = fmaxf(ix2 - ix1, 0.f) * fmaxf(iy2 - iy1, 0.f);
                        float uni = ari + ar - inter;
                        if (inter / fmaxf(uni, 1e-8f) > IOU_T) mj |= 1ull << i;
                    }
                }
            }
            u64 conf = __ballot(mj != 0ull);
            if (conf != 0ull) {                         // rare; wave-uniform
                u64 srcs = mj;
                #pragma unroll
                for (int d = 1; d < 64; d <<= 1) srcs |= shfl_xor_u64(srcs, d);
                wmS[wave][lane] = mj;
                __builtin_amdgcn_wave_barrier();

                u64 Cset = srcs | conf;
                u64 keptS = 0ull, rem = Cset;
                while (rem) {                           // tiny redundant scalar greedy
                    u64 t = rem, bestk = 0ull; int bi = -1;
                    while (t) {
                        int i = __ffsll(t) - 1; t &= t - 1;
                        u64 k = wkeyS[wave][i];
                        if (k > bestk) { bestk = k; bi = i; }
                    }
                    rem &= ~(1ull << bi);
                    if ((wmS[wave][bi] & keptS) == 0ull) keptS |= 1ull << bi;
                }
                if (lane < cnt && (mj & keptS) != 0ull)
                    atomicOr(&sm[orig >> 5], 1u << (orig & 31));
            }
        } else {
            // ---- exact wave-local fallback (r8/r10 pattern; ~never taken) ----
            volatile unsigned char* vf = fstate + off;
            for (int e = lane; e < cnt; e += 64) vf[e] = 0;
            __builtin_amdgcn_wave_barrier();
            int keptCount = 0;
            for (;;) {
                u64 best = 0ull; int bi = -1;
                for (int e = lane; e < cnt; e += 64)
                    if (vf[e] == 0) {
                        u64 kv = keys[clsList[off + e]];
                        if (kv > best) { best = kv; bi = e; }
                    }
                for (int d = 32; d >= 1; d >>= 1) {
                    u64 ob = shfl_xor_u64(best, d);
                    int obi = __shfl_xor(bi, d, 64);
                    if (ob > best) { best = ob; bi = obi; }
                }
                if (best == 0ull) break;
                keptCount++;
                int orig = (int)(u32)best;
                const float* q = P + orig * 6;
                float ax1 = q[0], ay1 = q[1], ax2 = q[2], ay2 = q[3];
                float aar = fmaxf(ax2 - ax1, 0.f) * fmaxf(ay2 - ay1, 0.f);
                if (lane == 0) vf[bi] = 1;
                __builtin_amdgcn_wave_barrier();
                for (int e = lane; e < cnt; e += 64) {
                    if (vf[e] == 0) {
                        u64 kv = keys[clsList[off + e]];
                        int o2 = (int)(u32)kv;
                        const float* q2 = P + o2 * 6;
                        float bx1 = q2[0], by1 = q2[1], bx2 = q2[2], by2 = q2[3];
                        float br = fmaxf(bx2 - bx1, 0.f) * fmaxf(by2 - by1, 0.f);
                        float ix1 = fmaxf(ax1, bx1), iy1 = fmaxf(ay1, by1);
                        float ix2 = fminf(ax2, bx2), iy2 = fminf(ay2, by2);
                        float inter = fmaxf(ix2 - ix1, 0.f) * fmaxf(iy2 - iy1, 0.f);
                        if (inter / fmaxf(aar + br - inter, 1e-8f) > IOU_T) {
                            vf[e] = 2;
                            atomicOr(&sm[o2 >> 5], 1u << (o2 & 31));
                        }
                    }
                }
                if (keptCount > MAX_PER_CLASS && lane == 0)
                    atomicOr(&sm[orig >> 5], 1u << (orig & 31));
                __builtin_amdgcn_wave_barrier();
            }
        }
    }
    __syncthreads();

    // ---- Phase 4: compaction + output (validated) ----
    for (int cc = wave; cc < 32; cc += 16) {
        u64 k = keys[cc * 64 + lane];
        int orig = (int)(u32)k;
        bool kp = ((k >> 32) != 0) && !((sm[orig >> 5] >> (orig & 31)) & 1u);
        u64 m = __ballot(kp);
        if (lane == 0) { keptM[cc] = m; kcnt[cc] = __popcll(m); }
    }
    __syncthreads();
    if (tid < 32) {
        int s = 0;
        for (int c2 = 0; c2 < tid; ++c2) s += kcnt[c2];
        kbase[tid] = s;
    }
    __syncthreads();

    float* boxes_out   = out + (size_t)b * MAX_DET * 4;
    float* scores_out  = out + (size_t)B * MAX_DET * 4 + (size_t)b * MAX_DET;
    float* classes_out = out + (size_t)B * MAX_DET * 5 + (size_t)b * MAX_DET;
    float* numdet_out  = out + (size_t)B * MAX_DET * 6 + b;

    for (int cc = wave; cc < 32; cc += 16) {
        u64 m = keptM[cc];
        bool kp = (m >> lane) & 1ull;
        int pos = kbase[cc] + __popcll(m & ((1ull << lane) - 1ull));
        if (kp && pos < MAX_DET) {
            u64 k = keys[cc * 64 + lane];
            int orig = (int)(u32)k;
            const float* q = P + orig * 6;
            boxes_out[pos * 4 + 0] = q[0];
            boxes_out[pos * 4 + 1] = q[1];
            boxes_out[pos * 4 + 2] = q[2];
            boxes_out[pos * 4 + 3] = q[3];
            scores_out[pos]  = __uint_as_float((u32)(k >> 32));
            classes_out[pos] = q[4];
        }
    }
    int total = kbase[31] + kcnt[31];
    int nd = total < MAX_DET ? total : MAX_DET;
    for (int p = nd + tid; p < MAX_DET; p += 1024) {
        boxes_out[p * 4 + 0] = 0.f;
        boxes_out[p * 4 + 1] = 0.f;
        boxes_out[p * 4 + 2] = 0.f;
        boxes_out[p * 4 + 3] = 0.f;
        scores_out[p]  = 0.f;
        classes_out[p] = 0.f;
    }
    if (tid == 0) *numdet_out = (float)nd;
}

extern "C" void kernel_launch(void* const* d_in, const int* in_sizes, int n_in,
                              void* d_out, int out_size, void* d_ws, size_t ws_size,
                              hipStream_t stream) {
    const float* pred = (const float*)d_in[0];
    float* out = (float*)d_out;
    const int B = in_sizes[0] / (NB * 6);
    nms_fused<<<B, 1024, 0, stream>>>(pred, out, B);
}

// Round 12
// 46.018 us; speedup vs baseline: 1.8595x; 1.3428x over previous
//
#include <hip/hip_runtime.h>
#include <stdint.h>

#define NB 2048
#define NCLASSES 80
#define CONF_T 0.05f
#define IOU_T 0.5f
#define MAX_DET 100
#define MAX_PER_CLASS 100

typedef unsigned long long u64;
typedef unsigned int u32;
typedef unsigned char u8;

__device__ __forceinline__ u64 shfl_xor_u64(u64 v, int mask) {
    int lo = (int)(u32)v, hi = (int)(u32)(v >> 32);
    lo = __shfl_xor(lo, mask, 64);
    hi = __shfl_xor(hi, mask, 64);
    return ((u64)(u32)hi << 32) | (u32)lo;
}

// ====================================================================
// One worker kernel, grid 88 x 512:
//  blocks 0..7   : per-batch pure LDS sort (r9-validated core) ->
//                  spin done[b]==80 -> atomic-read supBytes -> output.
//  blocks 8..87  : 8 waves, one (class,batch) pair each:
//                  self-bucket (r7) -> pair-matrix NMS (r11) ->
//                  supBytes exactly-once writes -> fence -> done++.
// Cross-block protocol: atomics + release/acquire fences only.
// ====================================================================
__global__ __launch_bounds__(512) void nms_one(const float* __restrict__ pred,
                                               u8* __restrict__ supBytes,
                                               u32* __restrict__ done,
                                               float* __restrict__ out, int B) {
    const int bid = blockIdx.x, tid = threadIdx.x;
    const int lane = tid & 63, wave = tid >> 6;            // 8 waves

    __shared__ u64 keys[NB];                               // 16 KB (sort role)
    __shared__ u32 smw[NB / 4];                            // 2 KB  (sort role)
    __shared__ u64 keptM[32];
    __shared__ int kcnt[32], kbase[32];
    __shared__ u64 wkeyS[8][64];                           // 4 KB  (class role)
    __shared__ float4 wb4S[8][64];                         // 8 KB
    __shared__ u64 wmS[8][64];                             // 4 KB
    __shared__ u8 fstate[8][NB];                           // 16 KB (fallback only)

    if (bid < 8) {
        // ============ SORT + EPILOGUE role (batch b = bid) ============
        const int b = bid;
        const float* P = pred + (size_t)b * NB * 6;

        const int sbase = wave * 256;
        const int iA = sbase + lane, iB = iA + 64, iC = iA + 128, iD = iA + 192;

        auto mkkey = [&](int i) -> u64 {
            float s = P[i * 6 + 5];
            return (s > CONF_T) ? (((u64)__float_as_uint(s) << 32) | (u32)i)
                                : (u64)(u32)i;
        };
        u64 A = mkkey(iA), Bv = mkkey(iB), C = mkkey(iC), D = mkkey(iD);

        auto loc = [&](u64& X, u64& Y, int ix, int k) {
            bool up = ((ix & k) == 0);
            u64 mx = X > Y ? X : Y, mn = X > Y ? Y : X;
            X = up ? mx : mn; Y = up ? mn : mx;
        };
        auto shf = [&](u64& V, int iv, int j, int k) {
            u64 p = shfl_xor_u64(V, j);
            bool low = ((lane & j) == 0);
            bool up  = ((iv & k) == 0);
            V = (low == up) ? (V > p ? V : p) : (V < p ? V : p);
        };
        auto tail = [&](int k, int jstart) {
            if (jstart >= 128) { loc(A, C, iA, k); loc(Bv, D, iB, k); }
            if (jstart >= 64)  { loc(A, Bv, iA, k); loc(C, D, iC, k); }
            for (int j = (jstart > 32 ? 32 : jstart); j >= 1; j >>= 1) {
                shf(A, iA, j, k); shf(Bv, iB, j, k); shf(C, iC, j, k); shf(D, iD, j, k);
            }
        };

        for (int k = 2; k <= 256; k <<= 1) tail(k, k >> 1);
        keys[iA] = A; keys[iB] = Bv; keys[iC] = C; keys[iD] = D;
        __syncthreads();

        for (int k = 512; k <= NB; k <<= 1) {
            for (int j = k >> 1; j >= 256; j >>= 1) {
                for (int pp = tid; pp < (NB >> 1); pp += 512) {
                    int i1 = ((pp & ~(j - 1)) << 1) | (pp & (j - 1));
                    int i2 = i1 + j;
                    bool up = ((i1 & k) == 0);
                    u64 a = keys[i1], c = keys[i2];
                    if (up ? (a < c) : (a > c)) { keys[i1] = c; keys[i2] = a; }
                }
                __syncthreads();
            }
            A = keys[iA]; Bv = keys[iB]; C = keys[iC]; D = keys[iD];
            tail(k, 128);
            keys[iA] = A; keys[iB] = Bv; keys[iC] = C; keys[iD] = D;
            __syncthreads();
        }

        // ---- wait for all 80 class waves of this batch ----
        if (tid == 0)
            while (atomicAdd(&done[b], 0u) < (u32)NCLASSES)
                __builtin_amdgcn_s_sleep(8);
        __syncthreads();
        __threadfence();                                   // acquire
        smw[tid] = atomicOr((u32*)(supBytes + (size_t)b * NB) + tid, 0u);
        __syncthreads();

        // ---- compaction + output (r11 phase-4, 8-wave stride) ----
        for (int cc = wave; cc < 32; cc += 8) {
            u64 k = keys[cc * 64 + lane];
            int orig = (int)(u32)k;
            bool kp = ((k >> 32) != 0) &&
                      (((smw[orig >> 2] >> ((orig & 3) * 8)) & 0xFFu) == 0u);
            u64 m = __ballot(kp);
            if (lane == 0) { keptM[cc] = m; kcnt[cc] = __popcll(m); }
        }
        __syncthreads();
        if (tid < 32) {
            int s = 0;
            for (int c2 = 0; c2 < tid; ++c2) s += kcnt[c2];
            kbase[tid] = s;
        }
        __syncthreads();

        float* boxes_out   = out + (size_t)b * MAX_DET * 4;
        float* scores_out  = out + (size_t)B * MAX_DET * 4 + (size_t)b * MAX_DET;
        float* classes_out = out + (size_t)B * MAX_DET * 5 + (size_t)b * MAX_DET;
        float* numdet_out  = out + (size_t)B * MAX_DET * 6 + b;

        for (int cc = wave; cc < 32; cc += 8) {
            u64 m = keptM[cc];
            bool kp = (m >> lane) & 1ull;
            int pos = kbase[cc] + __popcll(m & ((1ull << lane) - 1ull));
            if (kp && pos < MAX_DET) {
                u64 k = keys[cc * 64 + lane];
                int orig = (int)(u32)k;
                const float* q = P + orig * 6;
                boxes_out[pos * 4 + 0] = q[0];
                boxes_out[pos * 4 + 1] = q[1];
                boxes_out[pos * 4 + 2] = q[2];
                boxes_out[pos * 4 + 3] = q[3];
                scores_out[pos]  = __uint_as_float((u32)(k >> 32));
                classes_out[pos] = q[4];
            }
        }
        int total = kbase[31] + kcnt[31];
        int nd = total < MAX_DET ? total : MAX_DET;
        for (int p = nd + tid; p < MAX_DET; p += 512) {
            boxes_out[p * 4 + 0] = 0.f;
            boxes_out[p * 4 + 1] = 0.f;
            boxes_out[p * 4 + 2] = 0.f;
            boxes_out[p * 4 + 3] = 0.f;
            scores_out[p]  = 0.f;
            classes_out[p] = 0.f;
        }
        if (tid == 0) *numdet_out = (float)nd;
    } else {
        // ============ CLASS role: wave -> (batch, class) ============
        const int p = (bid - 8) * 8 + wave;                // 0..639
        const int b = p & 7, c = p >> 3;                   // 8 batches x 80 classes
        const float* P = pred + (size_t)b * NB * 6;
        u8* sb = supBytes + (size_t)b * NB;

        // ---- self-bucket: ballot-compact class c into per-wave LDS (r7) ----
        int cnt = 0;
        for (int base = 0; base < NB; base += 64) {
            int i = base + lane;
            float2 cs = *reinterpret_cast<const float2*>(P + i * 6 + 4);
            bool v = (cs.y > CONF_T) && ((int)cs.x == c);
            u64 m = __ballot(v);
            if (v) {
                int pos = cnt + __popcll(m & ((1ull << lane) - 1ull));
                if (pos < 64) {
                    float2 p01 = *reinterpret_cast<const float2*>(P + i * 6);
                    float2 p23 = *reinterpret_cast<const float2*>(P + i * 6 + 2);
                    wkeyS[wave][pos] = ((u64)__float_as_uint(cs.y) << 32) | (u32)i;
                    wb4S[wave][pos] = make_float4(p01.x, p01.y, p23.x, p23.y);
                }
            }
            cnt += __popcll(m);
        }
        __builtin_amdgcn_wave_barrier();

        if (cnt <= 64) {
            // ---- pair-matrix engine (r11-validated) + byte writes ----
            u64 mykey = 0ull; int orig = 0;
            float x1 = 0.f, y1 = 0.f, x2 = 0.f, y2 = 0.f, ar = 0.f;
            if (lane < cnt) {
                mykey = wkeyS[wave][lane];
                orig = (int)(u32)mykey;
                float4 bx = wb4S[wave][lane];
                x1 = bx.x; y1 = bx.y; x2 = bx.z; y2 = bx.w;
                ar = fmaxf(x2 - x1, 0.f) * fmaxf(y2 - y1, 0.f);
            }
            u64 mj = 0ull;
            if (lane < cnt) {
                for (int i = 0; i < cnt; ++i) {
                    u64 ki = wkeyS[wave][i];
                    if (ki > mykey) {
                        float4 bi = wb4S[wave][i];
                        float ari = fmaxf(bi.z - bi.x, 0.f) * fmaxf(bi.w - bi.y, 0.f);
                        float ix1 = fmaxf(bi.x, x1), iy1 = fmaxf(bi.y, y1);
                        float ix2 = fminf(bi.z, x2), iy2 = fminf(bi.w, y2);
                        float inter = fmaxf(ix2 - ix1, 0.f) * fmaxf(iy2 - iy1, 0.f);
                        float uni = ari + ar - inter;
                        if (inter / fmaxf(uni, 1e-8f) > IOU_T) mj |= 1ull << i;
                    }
                }
            }
            u64 conf = __ballot(mj != 0ull);
            bool sup = false;
            if (conf != 0ull) {                            // rare; wave-uniform
                u64 srcs = mj;
                #pragma unroll
                for (int d = 1; d < 64; d <<= 1) srcs |= shfl_xor_u64(srcs, d);
                wmS[wave][lane] = mj;
                __builtin_amdgcn_wave_barrier();
                u64 Cset = srcs | conf;
                u64 keptS = 0ull, rem = Cset;
                while (rem) {
                    u64 t = rem, bestk = 0ull; int bi = -1;
                    while (t) {
                        int i = __ffsll(t) - 1; t &= t - 1;
                        u64 k = wkeyS[wave][i];
                        if (k > bestk) { bestk = k; bi = i; }
                    }
                    rem &= ~(1ull << bi);
                    if ((wmS[wave][bi] & keptS) == 0ull) keptS |= 1ull << bi;
                }
                sup = (mj & keptS) != 0ull;
            }
            if (lane < cnt) sb[orig] = sup ? 1 : 0;        // exactly-once per valid orig
        } else {
            // ---- exact rescan selection-greedy fallback (~never taken) ----
            volatile u8* vf = fstate[wave];
            for (int o = lane; o < NB; o += 64) vf[o] = 0;
            __builtin_amdgcn_wave_barrier();
            int keptCount = 0;
            for (;;) {
                u64 best = 0ull; int bo = -1;
                for (int o = lane; o < NB; o += 64) {
                    if (vf[o]) continue;
                    float2 cs = *reinterpret_cast<const float2*>(P + o * 6 + 4);
                    if (cs.y > CONF_T && (int)cs.x == c) {
                        u64 k = ((u64)__float_as_uint(cs.y) << 32) | (u32)o;
                        if (k > best) { best = k; bo = o; }
                    }
                }
                for (int d = 32; d >= 1; d >>= 1) {
                    u64 ob = shfl_xor_u64(best, d);
                    int obo = __shfl_xor(bo, d, 64);
                    if (ob > best) { best = ob; bo = obo; }
                }
                if (best == 0ull) break;
                keptCount++;
                int orig = (int)(u32)best;
                if (lane == 0) {
                    vf[orig] = 1;
                    sb[orig] = (keptCount > MAX_PER_CLASS) ? 1 : 0;  // cap
                }
                __builtin_amdgcn_wave_barrier();
                const float* q = P + orig * 6;
                float ax1 = q[0], ay1 = q[1], ax2 = q[2], ay2 = q[3];
                float aar = fmaxf(ax2 - ax1, 0.f) * fmaxf(ay2 - ay1, 0.f);
                for (int o = lane; o < NB; o += 64) {
                    if (vf[o]) continue;
                    float2 cs = *reinterpret_cast<const float2*>(P + o * 6 + 4);
                    if (cs.y > CONF_T && (int)cs.x == c) {
                        const float* q2 = P + o * 6;
                        float bx1 = q2[0], by1 = q2[1], bx2 = q2[2], by2 = q2[3];
                        float br = fmaxf(bx2 - bx1, 0.f) * fmaxf(by2 - by1, 0.f);
                        float ix1 = fmaxf(ax1, bx1), iy1 = fmaxf(ay1, by1);
                        float ix2 = fminf(ax2, bx2), iy2 = fminf(ay2, by2);
                        float inter = fmaxf(ix2 - ix1, 0.f) * fmaxf(iy2 - iy1, 0.f);
                        if (inter / fmaxf(aar + br - inter, 1e-8f) > IOU_T) {
                            vf[o] = 2;
                            sb[o] = 1;
                        }
                    }
                }
                __builtin_amdgcn_wave_barrier();
            }
        }

        // ---- release + signal completion (all paths) ----
        __threadfence();
        __builtin_amdgcn_wave_barrier();
        if (lane == 0) atomicAdd(&done[b], 1u);
    }
}

// ====================================================================
// Fallback (round-0 monolithic, validated) for unexpected shapes/ws.
// ====================================================================
__global__ __launch_bounds__(1024) void nms_fallback(const float* __restrict__ pred,
                                                     float* __restrict__ out, int B) {
    const int b = blockIdx.x, tid = threadIdx.x;
    __shared__ u64 keys[NB];
    __shared__ float bx1[NB], by1[NB], bx2[NB], by2[NB];
    __shared__ int kc[NB];
    __shared__ int cnt[NCLASSES];
    __shared__ int overflow;
    const float* P = pred + (size_t)b * NB * 6;
    for (int i = tid; i < NB; i += 1024) {
        float s = P[i * 6 + 5];
        keys[i] = (s > CONF_T) ? (((u64)__float_as_uint(s) << 32) | (uint32_t)i)
                               : (u64)(uint32_t)i;
    }
    __syncthreads();
    for (int k = 2; k <= NB; k <<= 1)
        for (int j = k >> 1; j > 0; j >>= 1) {
            for (int i = tid; i < NB; i += 1024) {
                int ixj = i ^ j;
                if (ixj > i) {
                    u64 a = keys[i], c = keys[ixj];
                    bool up = ((i & k) == 0);
                    if (up ? (a < c) : (a > c)) { keys[i] = c; keys[ixj] = a; }
                }
            }
            __syncthreads();
        }
    for (int i = tid; i < NB; i += 1024) {
        u64 k = keys[i];
        int orig = (int)(uint32_t)k;
        const float* q = P + orig * 6;
        bx1[i] = q[0]; by1[i] = q[1]; bx2[i] = q[2]; by2[i] = q[3];
        kc[i] = ((k >> 32) != 0) ? (int)q[4] : -1;
    }
    __syncthreads();
    bool dirty = false;
    for (int i = 0; i < NB - 1; ++i) {
        if (i == 0 || dirty) { __syncthreads(); dirty = false; }
        int ci = kc[i];
        if (ci < 0) continue;
        dirty = true;
        float x1i = bx1[i], y1i = by1[i], x2i = bx2[i], y2i = by2[i];
        float ai = fmaxf(x2i - x1i, 0.f) * fmaxf(y2i - y1i, 0.f);
        for (int j = i + 1 + tid; j < NB; j += 1024) {
            if (kc[j] != ci) continue;
            float ix1 = fmaxf(x1i, bx1[j]), iy1 = fmaxf(y1i, by1[j]);
            float ix2 = fminf(x2i, bx2[j]), iy2 = fminf(y2i, by2[j]);
            float inter = fmaxf(ix2 - ix1, 0.f) * fmaxf(iy2 - iy1, 0.f);
            float aj = fmaxf(bx2[j] - bx1[j], 0.f) * fmaxf(by2[j] - by1[j], 0.f);
            if (inter / fmaxf(ai + aj - inter, 1e-8f) > IOU_T) kc[j] = -1;
        }
    }
    __syncthreads();
    for (int i = tid; i < NCLASSES; i += 1024) cnt[i] = 0;
    if (tid == 0) overflow = 0;
    __syncthreads();
    for (int i = tid; i < NB; i += 1024) if (kc[i] >= 0) atomicAdd(&cnt[kc[i]], 1);
    __syncthreads();
    if (tid < NCLASSES && cnt[tid] > MAX_PER_CLASS) atomicOr(&overflow, 1);
    __syncthreads();
    if (overflow) {
        if (tid == 0) {
            for (int c = 0; c < NCLASSES; ++c) cnt[c] = 0;
            for (int i = 0; i < NB; ++i)
                if (kc[i] >= 0 && ++cnt[kc[i]] > MAX_PER_CLASS) kc[i] = -1;
        }
        __syncthreads();
    }
    if (tid < 64) {
        const int lane = tid;
        float* boxes_out   = out + (size_t)b * MAX_DET * 4;
        float* scores_out  = out + (size_t)B * MAX_DET * 4 + (size_t)b * MAX_DET;
        float* classes_out = out + (size_t)B * MAX_DET * 5 + (size_t)b * MAX_DET;
        float* numdet_out  = out + (size_t)B * MAX_DET * 6 + b;
        int running = 0;
        for (int chunk = 0; chunk < NB / 64; ++chunk) {
            int j = chunk * 64 + lane;
            int c = kc[j];
            bool k = (c >= 0);
            u64 m = __ballot(k);
            int pos = running + __popcll(m & ((1ull << lane) - 1ull));
            if (k && pos < MAX_DET) {
                boxes_out[pos * 4 + 0] = bx1[j];
                boxes_out[pos * 4 + 1] = by1[j];
                boxes_out[pos * 4 + 2] = bx2[j];
                boxes_out[pos * 4 + 3] = by2[j];
                scores_out[pos]  = __uint_as_float((uint32_t)(keys[j] >> 32));
                classes_out[pos] = (float)c;
            }
            running += __popcll(m);
        }
        int nd = running < MAX_DET ? running : MAX_DET;
        for (int p = nd + lane; p < MAX_DET; p += 64) {
            boxes_out[p * 4 + 0] = 0.f; boxes_out[p * 4 + 1] = 0.f;
            boxes_out[p * 4 + 2] = 0.f; boxes_out[p * 4 + 3] = 0.f;
            scores_out[p] = 0.f; classes_out[p] = 0.f;
        }
        if (lane == 0) *numdet_out = (float)nd;
    }
}

extern "C" void kernel_launch(void* const* d_in, const int* in_sizes, int n_in,
                              void* d_out, int out_size, void* d_ws, size_t ws_size,
                              hipStream_t stream) {
    const float* pred = (const float*)d_in[0];
    float* out = (float*)d_out;
    const int B = in_sizes[0] / (NB * 6);

    u8* supBytes = (u8*)d_ws;                          // B*2048 bytes
    u32* done = (u32*)(supBytes + (size_t)B * NB);     // B u32
    const size_t need = (size_t)B * NB + (size_t)B * 4;

    if (B != 8 || ws_size < need) {
        nms_fallback<<<B, 1024, 0, stream>>>(pred, out, B);
        return;
    }

    hipMemsetAsync(done, 0, (size_t)B * 4, stream);    // 32 B; graph-safe (r7)
    nms_one<<<8 + NCLASSES, 512, 0, stream>>>(pred, supBytes, done, out, B);
}

// Round 13
// 27.090 us; speedup vs baseline: 3.1587x; 1.6987x over previous
//
#include <hip/hip_runtime.h>
#include <stdint.h>

#define NB 2048
#define NCLASSES 80
#define CONF_T 0.05f
#define IOU_T 0.5f
#define MAX_DET 100
#define MAX_PER_CLASS 100

typedef unsigned long long u64;
typedef unsigned int u32;
typedef unsigned char u8;

__device__ __forceinline__ u64 shfl_xor_u64(u64 v, int mask) {
    int lo = (int)(u32)v, hi = (int)(u32)(v >> 32);
    lo = __shfl_xor(lo, mask, 64);
    hi = __shfl_xor(hi, mask, 64);
    return ((u64)(u32)hi << 32) | (u32)lo;
}

// ====================================================================
// Kernel A, grid (8 + B*10) x 512, NO cross-block sync:
//  blocks 0..7        : per-batch LDS bitonic sort (r12-validated) ->
//                       write keysG. Done.
//  blocks 8..8+B*10-1 : batch b = idx/10 (uniform per block); 8 waves
//                       cover classes (idx%10)*8+wave. Stage (cls,score)
//                       to LDS once per block, per-wave self-bucket +
//                       pair-matrix NMS (r11/r12-validated engine),
//                       write supBytes[orig] in {0,1} for EVERY valid
//                       box (exactly-once => no memset, poison-safe).
// ====================================================================
__global__ __launch_bounds__(512) void k_work(const float* __restrict__ pred,
                                              u64* __restrict__ keysG,
                                              u8* __restrict__ supBytes) {
    const int bid = blockIdx.x, tid = threadIdx.x;
    const int lane = tid & 63, wave = tid >> 6;            // 8 waves

    __shared__ __align__(16) char smem[49152];             // 48 KB, role-overlaid
    u64*    keys = (u64*)smem;                             // sort: 16 KB
    float2* csS  = (float2*)smem;                          // class: 16 KB
    u64*    wkey = (u64*)(smem + 16384);                   // class: 4 KB  [8][64]
    float4* wb4  = (float4*)(smem + 20480);                // class: 8 KB  [8][64]
    u64*    wm   = (u64*)(smem + 28672);                   // class: 4 KB  [8][64]
    u8*     fst  = (u8*)(smem + 32768);                    // class: 16 KB [8][2048]

    if (bid < 8) {
        // ================= SORT role (batch b = bid) =================
        const int b = bid;
        const float* P = pred + (size_t)b * NB * 6;

        const int sbase = wave * 256;
        const int iA = sbase + lane, iB = iA + 64, iC = iA + 128, iD = iA + 192;

        auto mkkey = [&](int i) -> u64 {
            float s = P[i * 6 + 5];
            return (s > CONF_T) ? (((u64)__float_as_uint(s) << 32) | (u32)i)
                                : (u64)(u32)i;
        };
        u64 A = mkkey(iA), Bv = mkkey(iB), C = mkkey(iC), D = mkkey(iD);

        auto loc = [&](u64& X, u64& Y, int ix, int k) {
            bool up = ((ix & k) == 0);
            u64 mx = X > Y ? X : Y, mn = X > Y ? Y : X;
            X = up ? mx : mn; Y = up ? mn : mx;
        };
        auto shf = [&](u64& V, int iv, int j, int k) {
            u64 p = shfl_xor_u64(V, j);
            bool low = ((lane & j) == 0);
            bool up  = ((iv & k) == 0);
            V = (low == up) ? (V > p ? V : p) : (V < p ? V : p);
        };
        auto tail = [&](int k, int jstart) {
            if (jstart >= 128) { loc(A, C, iA, k); loc(Bv, D, iB, k); }
            if (jstart >= 64)  { loc(A, Bv, iA, k); loc(C, D, iC, k); }
            for (int j = (jstart > 32 ? 32 : jstart); j >= 1; j >>= 1) {
                shf(A, iA, j, k); shf(Bv, iB, j, k); shf(C, iC, j, k); shf(D, iD, j, k);
            }
        };

        for (int k = 2; k <= 256; k <<= 1) tail(k, k >> 1);
        keys[iA] = A; keys[iB] = Bv; keys[iC] = C; keys[iD] = D;
        __syncthreads();

        for (int k = 512; k <= NB; k <<= 1) {
            for (int j = k >> 1; j >= 256; j >>= 1) {
                for (int pp = tid; pp < (NB >> 1); pp += 512) {
                    int i1 = ((pp & ~(j - 1)) << 1) | (pp & (j - 1));
                    int i2 = i1 + j;
                    bool up = ((i1 & k) == 0);
                    u64 a = keys[i1], c = keys[i2];
                    if (up ? (a < c) : (a > c)) { keys[i1] = c; keys[i2] = a; }
                }
                __syncthreads();
            }
            A = keys[iA]; Bv = keys[iB]; C = keys[iC]; D = keys[iD];
            tail(k, 128);
            keys[iA] = A; keys[iB] = Bv; keys[iC] = C; keys[iD] = D;
            __syncthreads();
        }

        for (int i = tid; i < NB; i += 512)
            keysG[(size_t)b * NB + i] = keys[i];
    } else {
        // ================= CLASS role =================
        const int idx = bid - 8;
        const int b = idx / 10;                            // uniform per block
        const int c = (idx % 10) * 8 + wave;               // this wave's class
        const float* P = pred + (size_t)b * NB * 6;
        u8* sb = supBytes + (size_t)b * NB;

        // ---- stage (cls,score) once per block, coalesced-ish ----
        for (int i = tid; i < NB; i += 512)
            csS[i] = *reinterpret_cast<const float2*>(P + i * 6 + 4);
        __syncthreads();

        u64* wkeyW = wkey + wave * 64;
        float4* wb4W = wb4 + wave * 64;
        u64* wmW = wm + wave * 64;

        // ---- self-bucket class c from LDS (r7/r12-validated pattern) ----
        int cnt = 0;
        for (int base = 0; base < NB; base += 64) {
            int i = base + lane;
            float2 cs = csS[i];
            bool v = (cs.y > CONF_T) && ((int)cs.x == c);
            u64 m = __ballot(v);
            if (v) {
                int pos = cnt + __popcll(m & ((1ull << lane) - 1ull));
                if (pos < 64) {
                    float2 p01 = *reinterpret_cast<const float2*>(P + i * 6);
                    float2 p23 = *reinterpret_cast<const float2*>(P + i * 6 + 2);
                    wkeyW[pos] = ((u64)__float_as_uint(cs.y) << 32) | (u32)i;
                    wb4W[pos] = make_float4(p01.x, p01.y, p23.x, p23.y);
                }
            }
            cnt += __popcll(m);
        }
        __builtin_amdgcn_wave_barrier();

        if (cnt <= 64) {
            // ---- pair-matrix engine (r11/r12-validated) ----
            u64 mykey = 0ull; int orig = 0;
            float x1 = 0.f, y1 = 0.f, x2 = 0.f, y2 = 0.f, ar = 0.f;
            if (lane < cnt) {
                mykey = wkeyW[lane];
                orig = (int)(u32)mykey;
                float4 bx = wb4W[lane];
                x1 = bx.x; y1 = bx.y; x2 = bx.z; y2 = bx.w;
                ar = fmaxf(x2 - x1, 0.f) * fmaxf(y2 - y1, 0.f);
            }
            u64 mj = 0ull;
            if (lane < cnt) {
                for (int i = 0; i < cnt; ++i) {
                    u64 ki = wkeyW[i];
                    if (ki > mykey) {
                        float4 bi = wb4W[i];
                        float ari = fmaxf(bi.z - bi.x, 0.f) * fmaxf(bi.w - bi.y, 0.f);
                        float ix1 = fmaxf(bi.x, x1), iy1 = fmaxf(bi.y, y1);
                        float ix2 = fminf(bi.z, x2), iy2 = fminf(bi.w, y2);
                        float inter = fmaxf(ix2 - ix1, 0.f) * fmaxf(iy2 - iy1, 0.f);
                        float uni = ari + ar - inter;
                        if (inter / fmaxf(uni, 1e-8f) > IOU_T) mj |= 1ull << i;
                    }
                }
            }
            u64 conf = __ballot(mj != 0ull);
            bool sup = false;
            if (conf != 0ull) {                            // rare; wave-uniform
                u64 srcs = mj;
                #pragma unroll
                for (int d = 1; d < 64; d <<= 1) srcs |= shfl_xor_u64(srcs, d);
                wmW[lane] = mj;
                __builtin_amdgcn_wave_barrier();
                u64 Cset = srcs | conf;
                u64 keptS = 0ull, rem = Cset;
                while (rem) {                              // tiny redundant scalar greedy
                    u64 t = rem, bestk = 0ull; int bi = -1;
                    while (t) {
                        int i = __ffsll(t) - 1; t &= t - 1;
                        u64 k = wkeyW[i];
                        if (k > bestk) { bestk = k; bi = i; }
                    }
                    rem &= ~(1ull << bi);
                    if ((wmW[bi] & keptS) == 0ull) keptS |= 1ull << bi;
                }
                sup = (mj & keptS) != 0ull;
            }
            if (lane < cnt) sb[orig] = sup ? 1 : 0;        // exactly-once per valid box
        } else {
            // ---- exact LDS-rescan selection-greedy fallback (~never) ----
            volatile u8* vf = fst + wave * NB;
            for (int o = lane; o < NB; o += 64) vf[o] = 0;
            __builtin_amdgcn_wave_barrier();
            int keptCount = 0;
            for (;;) {
                u64 best = 0ull; int bo = -1;
                for (int o = lane; o < NB; o += 64) {
                    if (vf[o]) continue;
                    float2 cs = csS[o];
                    if (cs.y > CONF_T && (int)cs.x == c) {
                        u64 k = ((u64)__float_as_uint(cs.y) << 32) | (u32)o;
                        if (k > best) { best = k; bo = o; }
                    }
                }
                for (int d = 32; d >= 1; d >>= 1) {
                    u64 ob = shfl_xor_u64(best, d);
                    int obo = __shfl_xor(bo, d, 64);
                    if (ob > best) { best = ob; bo = obo; }
                }
                if (best == 0ull) break;
                keptCount++;
                int orig = (int)(u32)best;
                if (lane == 0) {
                    vf[orig] = 1;
                    sb[orig] = (keptCount > MAX_PER_CLASS) ? 1 : 0;  // cap
                }
                __builtin_amdgcn_wave_barrier();
                const float* q = P + orig * 6;
                float ax1 = q[0], ay1 = q[1], ax2 = q[2], ay2 = q[3];
                float aar = fmaxf(ax2 - ax1, 0.f) * fmaxf(ay2 - ay1, 0.f);
                for (int o = lane; o < NB; o += 64) {
                    if (vf[o]) continue;
                    float2 cs = csS[o];
                    if (cs.y > CONF_T && (int)cs.x == c) {
                        const float* q2 = P + o * 6;
                        float bx1 = q2[0], by1 = q2[1], bx2 = q2[2], by2 = q2[3];
                        float br = fmaxf(bx2 - bx1, 0.f) * fmaxf(by2 - by1, 0.f);
                        float ix1 = fmaxf(ax1, bx1), iy1 = fmaxf(ay1, by1);
                        float ix2 = fminf(ax2, bx2), iy2 = fminf(ay2, by2);
                        float inter = fmaxf(ix2 - ix1, 0.f) * fmaxf(iy2 - iy1, 0.f);
                        if (inter / fmaxf(aar + br - inter, 1e-8f) > IOU_T) {
                            vf[o] = 2;
                            sb[o] = 1;
                        }
                    }
                }
                __builtin_amdgcn_wave_barrier();
            }
        }
    }
}

// ====================================================================
// Kernel B (per batch, 256 thr): plain-load keysG + supBytes (kernel
// boundary = sync), compaction + output (r12-epilogue-validated).
// ====================================================================
__global__ __launch_bounds__(256) void k_out2(const float* __restrict__ pred,
                                              const u64* __restrict__ keysG,
                                              const u8* __restrict__ supBytes,
                                              float* __restrict__ out, int B) {
    const int b = blockIdx.x, tid = threadIdx.x;
    const int wave = tid >> 6, lane = tid & 63;
    __shared__ u32 smw[NB / 4];                            // 2 KB byte-map
    __shared__ u64 keptM[32];
    __shared__ int kcnt[32], kbase[32];

    const u32* sw = (const u32*)(supBytes + (size_t)b * NB);
    for (int i = tid; i < NB / 4; i += 256) smw[i] = sw[i];
    __syncthreads();

    const u64* kg = keysG + (size_t)b * NB;
    const float* P = pred + (size_t)b * NB * 6;

    for (int cc = wave; cc < 32; cc += 4) {
        u64 k = kg[cc * 64 + lane];
        int orig = (int)(u32)k;
        bool kp = ((k >> 32) != 0) &&
                  (((smw[orig >> 2] >> ((orig & 3) * 8)) & 0xFFu) == 0u);
        u64 m = __ballot(kp);
        if (lane == 0) { keptM[cc] = m; kcnt[cc] = __popcll(m); }
    }
    __syncthreads();
    if (tid < 32) {
        int s = 0;
        for (int c2 = 0; c2 < tid; ++c2) s += kcnt[c2];
        kbase[tid] = s;
    }
    __syncthreads();

    float* boxes_out   = out + (size_t)b * MAX_DET * 4;
    float* scores_out  = out + (size_t)B * MAX_DET * 4 + (size_t)b * MAX_DET;
    float* classes_out = out + (size_t)B * MAX_DET * 5 + (size_t)b * MAX_DET;
    float* numdet_out  = out + (size_t)B * MAX_DET * 6 + b;

    for (int cc = wave; cc < 32; cc += 4) {
        u64 m = keptM[cc];
        bool kp = (m >> lane) & 1ull;
        int pos = kbase[cc] + __popcll(m & ((1ull << lane) - 1ull));
        if (kp && pos < MAX_DET) {
            u64 k = kg[cc * 64 + lane];
            int orig = (int)(u32)k;
            const float* q = P + orig * 6;
            boxes_out[pos * 4 + 0] = q[0];
            boxes_out[pos * 4 + 1] = q[1];
            boxes_out[pos * 4 + 2] = q[2];
            boxes_out[pos * 4 + 3] = q[3];
            scores_out[pos]  = __uint_as_float((u32)(k >> 32));
            classes_out[pos] = q[4];
        }
    }
    int total = kbase[31] + kcnt[31];
    int nd = total < MAX_DET ? total : MAX_DET;
    for (int p = nd + tid; p < MAX_DET; p += 256) {
        boxes_out[p * 4 + 0] = 0.f;
        boxes_out[p * 4 + 1] = 0.f;
        boxes_out[p * 4 + 2] = 0.f;
        boxes_out[p * 4 + 3] = 0.f;
        scores_out[p]  = 0.f;
        classes_out[p] = 0.f;
    }
    if (tid == 0) *numdet_out = (float)nd;
}

// ====================================================================
// Fallback (round-0 monolithic, validated) for unexpected shapes/ws.
// ====================================================================
__global__ __launch_bounds__(1024) void nms_fallback(const float* __restrict__ pred,
                                                     float* __restrict__ out, int B) {
    const int b = blockIdx.x, tid = threadIdx.x;
    __shared__ u64 keys[NB];
    __shared__ float bx1[NB], by1[NB], bx2[NB], by2[NB];
    __shared__ int kc[NB];
    __shared__ int cnt[NCLASSES];
    __shared__ int overflow;
    const float* P = pred + (size_t)b * NB * 6;
    for (int i = tid; i < NB; i += 1024) {
        float s = P[i * 6 + 5];
        keys[i] = (s > CONF_T) ? (((u64)__float_as_uint(s) << 32) | (uint32_t)i)
                               : (u64)(uint32_t)i;
    }
    __syncthreads();
    for (int k = 2; k <= NB; k <<= 1)
        for (int j = k >> 1; j > 0; j >>= 1) {
            for (int i = tid; i < NB; i += 1024) {
                int ixj = i ^ j;
                if (ixj > i) {
                    u64 a = keys[i], c = keys[ixj];
                    bool up = ((i & k) == 0);
                    if (up ? (a < c) : (a > c)) { keys[i] = c; keys[ixj] = a; }
                }
            }
            __syncthreads();
        }
    for (int i = tid; i < NB; i += 1024) {
        u64 k = keys[i];
        int orig = (int)(uint32_t)k;
        const float* q = P + orig * 6;
        bx1[i] = q[0]; by1[i] = q[1]; bx2[i] = q[2]; by2[i] = q[3];
        kc[i] = ((k >> 32) != 0) ? (int)q[4] : -1;
    }
    __syncthreads();
    bool dirty = false;
    for (int i = 0; i < NB - 1; ++i) {
        if (i == 0 || dirty) { __syncthreads(); dirty = false; }
        int ci = kc[i];
        if (ci < 0) continue;
        dirty = true;
        float x1i = bx1[i], y1i = by1[i], x2i = bx2[i], y2i = by2[i];
        float ai = fmaxf(x2i - x1i, 0.f) * fmaxf(y2i - y1i, 0.f);
        for (int j = i + 1 + tid; j < NB; j += 1024) {
            if (kc[j] != ci) continue;
            float ix1 = fmaxf(x1i, bx1[j]), iy1 = fmaxf(y1i, by1[j]);
            float ix2 = fminf(x2i, bx2[j]), iy2 = fminf(y2i, by2[j]);
            float inter = fmaxf(ix2 - ix1, 0.f) * fmaxf(iy2 - iy1, 0.f);
            float aj = fmaxf(bx2[j] - bx1[j], 0.f) * fmaxf(by2[j] - by1[j], 0.f);
            if (inter / fmaxf(ai + aj - inter, 1e-8f) > IOU_T) kc[j] = -1;
        }
    }
    __syncthreads();
    for (int i = tid; i < NCLASSES; i += 1024) cnt[i] = 0;
    if (tid == 0) overflow = 0;
    __syncthreads();
    for (int i = tid; i < NB; i += 1024) if (kc[i] >= 0) atomicAdd(&cnt[kc[i]], 1);
    __syncthreads();
    if (tid < NCLASSES && cnt[tid] > MAX_PER_CLASS) atomicOr(&overflow, 1);
    __syncthreads();
    if (overflow) {
        if (tid == 0) {
            for (int c = 0; c < NCLASSES; ++c) cnt[c] = 0;
            for (int i = 0; i < NB; ++i)
                if (kc[i] >= 0 && ++cnt[kc[i]] > MAX_PER_CLASS) kc[i] = -1;
        }
        __syncthreads();
    }
    if (tid < 64) {
        const int lane = tid;
        float* boxes_out   = out + (size_t)b * MAX_DET * 4;
        float* scores_out  = out + (size_t)B * MAX_DET * 4 + (size_t)b * MAX_DET;
        float* classes_out = out + (size_t)B * MAX_DET * 5 + (size_t)b * MAX_DET;
        float* numdet_out  = out + (size_t)B * MAX_DET * 6 + b;
        int running = 0;
        for (int chunk = 0; chunk < NB / 64; ++chunk) {
            int j = chunk * 64 + lane;
            int c = kc[j];
            bool k = (c >= 0);
            u64 m = __ballot(k);
            int pos = running + __popcll(m & ((1ull << lane) - 1ull));
            if (k && pos < MAX_DET) {
                boxes_out[pos * 4 + 0] = bx1[j];
                boxes_out[pos * 4 + 1] = by1[j];
                boxes_out[pos * 4 + 2] = bx2[j];
                boxes_out[pos * 4 + 3] = by2[j];
                scores_out[pos]  = __uint_as_float((uint32_t)(keys[j] >> 32));
                classes_out[pos] = (float)c;
            }
            running += __popcll(m);
        }
        int nd = running < MAX_DET ? running : MAX_DET;
        for (int p = nd + lane; p < MAX_DET; p += 64) {
            boxes_out[p * 4 + 0] = 0.f; boxes_out[p * 4 + 1] = 0.f;
            boxes_out[p * 4 + 2] = 0.f; boxes_out[p * 4 + 3] = 0.f;
            scores_out[p] = 0.f; classes_out[p] = 0.f;
        }
        if (lane == 0) *numdet_out = (float)nd;
    }
}

extern "C" void kernel_launch(void* const* d_in, const int* in_sizes, int n_in,
                              void* d_out, int out_size, void* d_ws, size_t ws_size,
                              hipStream_t stream) {
    const float* pred = (const float*)d_in[0];
    float* out = (float*)d_out;
    const int B = in_sizes[0] / (NB * 6);
    const size_t nBox = (size_t)B * NB;

    u64* keysG = (u64*)d_ws;                           // B*2048 u64
    u8* supBytes = (u8*)(keysG + nBox);                // B*2048 bytes
    const size_t need = nBox * 8 + nBox;

    if (B != 8 || ws_size < need) {
        nms_fallback<<<B, 1024, 0, stream>>>(pred, out, B);
        return;
    }

    k_work<<<8 + B * 10, 512, 0, stream>>>(pred, keysG, supBytes);
    k_out2<<<B, 256, 0, stream>>>(pred, keysG, supBytes, out, B);
}